// Round 1
// baseline (2449.964 us; speedup 1.0000x reference)
//
#include <hip/hip_runtime.h>
#include <math.h>

#define N_NODES 100000
#define LN_EPS 1e-5f

// ---------------- degree ----------------
__global__ void zero_kernel(float* __restrict__ p, int n) {
    int i = blockIdx.x * blockDim.x + threadIdx.x;
    if (i < n) p[i] = 0.f;
}

__global__ void deg_count(const int* __restrict__ dst, float* __restrict__ deg, int E) {
    int e = blockIdx.x * blockDim.x + threadIdx.x;
    if (e < E) {
        int d = dst[e];
        if ((unsigned)d < (unsigned)N_NODES) atomicAdd(&deg[d], 1.f);
    }
}

__global__ void deg_to_dinv(float* __restrict__ deg, int n) {
    int i = blockIdx.x * blockDim.x + threadIdx.x;
    if (i < n) deg[i] = rsqrtf(deg[i] + 1.f);
}

// ---------------- gemm (X[n,IN_C] @ W[IN_C,OUT_C] (+ bias)) ----------------
template <int IN_C, int OUT_C>
__global__ void gemm_bias(const float* __restrict__ X, const float* __restrict__ W,
                          const float* __restrict__ bias, float* __restrict__ Y, int n) {
    __shared__ float sW[IN_C * OUT_C];
    for (int i = threadIdx.x; i < IN_C * OUT_C; i += blockDim.x) sW[i] = W[i];
    __syncthreads();
    constexpr int NPB = 256 / OUT_C;  // nodes per block
    int node = blockIdx.x * NPB + threadIdx.x / OUT_C;
    int j = threadIdx.x % OUT_C;
    if (node >= n) return;
    const float* xr = X + (size_t)node * IN_C;
    float sum = 0.f;
#pragma unroll
    for (int k = 0; k < IN_C; ++k) sum += xr[k] * sW[k * OUT_C + j];
    if (bias) sum += bias[j];
    Y[(size_t)node * OUT_C + j] = sum;
}

// ---------------- aggregation ----------------
// agg = xw * dinv^2 (self loop) + bias
__global__ void agg_init(const float* __restrict__ xw, const float* __restrict__ dinv,
                         const float* __restrict__ bias, float* __restrict__ agg,
                         int n, int C) {
    int i = blockIdx.x * blockDim.x + threadIdx.x;
    if (i < n * C) {
        int node = i / C;
        int j = i - node * C;
        float di = dinv[node];
        agg[i] = xw[i] * di * di + bias[j];
    }
}

template <int C>
__global__ void scatter_edges(const int* __restrict__ src, const int* __restrict__ dst,
                              const float* __restrict__ xw, const float* __restrict__ dinv,
                              float* __restrict__ agg, int E) {
    int t = blockIdx.x * blockDim.x + threadIdx.x;
    int e = t / C;
    int j = t - e * C;
    if (e >= E) return;
    int s = src[e], d = dst[e];
    if ((unsigned)s >= (unsigned)N_NODES || (unsigned)d >= (unsigned)N_NODES) return;
    float norm = dinv[s] * dinv[d];
    atomicAdd(&agg[(size_t)d * C + j], xw[(size_t)s * C + j] * norm);
}

// ---------------- layernorm + elu (one wave per node) ----------------
template <int C>
__global__ void ln_elu(float* __restrict__ h, const float* __restrict__ g,
                       const float* __restrict__ be, int n) {
    int wave = threadIdx.x >> 6;
    int lane = threadIdx.x & 63;
    int node = blockIdx.x * 4 + wave;
    if (node >= n) return;
    float* row = h + (size_t)node * C;
    constexpr int PER = (C + 63) / 64;
    float v[PER];
    float sum = 0.f, sq = 0.f;
#pragma unroll
    for (int idx = 0; idx < PER; ++idx) {
        int c = lane + idx * 64;
        float x = (c < C) ? row[c] : 0.f;
        v[idx] = x;
        sum += x;
        sq += x * x;
    }
#pragma unroll
    for (int off = 32; off > 0; off >>= 1) {
        sum += __shfl_xor(sum, off, 64);
        sq += __shfl_xor(sq, off, 64);
    }
    float mu = sum / C;
    float var = sq / C - mu * mu;
    float rs = rsqrtf(var + LN_EPS);
#pragma unroll
    for (int idx = 0; idx < PER; ++idx) {
        int c = lane + idx * 64;
        if (c < C) {
            float y = (v[idx] - mu) * rs * g[c] + be[c];
            row[c] = y > 0.f ? y : expm1f(y);
        }
    }
}

extern "C" void kernel_launch(void* const* d_in, const int* in_sizes, int n_in,
                              void* d_out, int out_size, void* d_ws, size_t ws_size,
                              hipStream_t stream) {
    const float* x  = (const float*)d_in[0];
    const int* ei   = (const int*)d_in[1];
    const float* W1 = (const float*)d_in[2];
    const float* b1 = (const float*)d_in[3];
    const float* g1 = (const float*)d_in[4];
    const float* be1= (const float*)d_in[5];
    const float* W2 = (const float*)d_in[6];
    const float* b2 = (const float*)d_in[7];
    const float* g2 = (const float*)d_in[8];
    const float* be2= (const float*)d_in[9];
    const float* W3 = (const float*)d_in[10];
    const float* b3 = (const float*)d_in[11];
    const float* g3 = (const float*)d_in[12];
    const float* be3= (const float*)d_in[13];
    const float* lw1= (const float*)d_in[14];
    const float* lb1= (const float*)d_in[15];
    const float* g4 = (const float*)d_in[16];
    const float* be4= (const float*)d_in[17];
    const float* lw2= (const float*)d_in[18];
    const float* lb2= (const float*)d_in[19];
    float* out = (float*)d_out;

    const int E = in_sizes[1] / 2;
    const int* src = ei;
    const int* dst = ei + E;

    float* ws0  = (float*)d_ws;                       // N*128
    float* ws1  = ws0 + (size_t)N_NODES * 128;        // N*128
    float* dinv = ws1 + (size_t)N_NODES * 128;        // N

    const int N = N_NODES;
    auto cdiv = [](long long a, long long b) { return (int)((a + b - 1) / b); };

    // degree -> dinv
    zero_kernel<<<cdiv(N, 256), 256, 0, stream>>>(dinv, N);
    deg_count<<<cdiv(E, 256), 256, 0, stream>>>(dst, dinv, E);
    deg_to_dinv<<<cdiv(N, 256), 256, 0, stream>>>(dinv, N);

    // Layer 1: 128 -> 64
    gemm_bias<128, 64><<<cdiv(N, 4), 256, 0, stream>>>(x, W1, nullptr, ws0, N);
    agg_init<<<cdiv((long long)N * 64, 256), 256, 0, stream>>>(ws0, dinv, b1, ws1, N, 64);
    scatter_edges<64><<<cdiv((long long)E * 64, 256), 256, 0, stream>>>(src, dst, ws0, dinv, ws1, E);
    ln_elu<64><<<cdiv(N, 4), 256, 0, stream>>>(ws1, g1, be1, N);

    // Layer 2: 64 -> 128
    gemm_bias<64, 128><<<cdiv(N, 2), 256, 0, stream>>>(ws1, W2, nullptr, ws0, N);
    agg_init<<<cdiv((long long)N * 128, 256), 256, 0, stream>>>(ws0, dinv, b2, ws1, N, 128);
    scatter_edges<128><<<cdiv((long long)E * 128, 256), 256, 0, stream>>>(src, dst, ws0, dinv, ws1, E);
    ln_elu<128><<<cdiv(N, 4), 256, 0, stream>>>(ws1, g2, be2, N);

    // Layer 3: 128 -> 64
    gemm_bias<128, 64><<<cdiv(N, 4), 256, 0, stream>>>(ws1, W3, nullptr, ws0, N);
    agg_init<<<cdiv((long long)N * 64, 256), 256, 0, stream>>>(ws0, dinv, b3, ws1, N, 64);
    scatter_edges<64><<<cdiv((long long)E * 64, 256), 256, 0, stream>>>(src, dst, ws0, dinv, ws1, E);
    ln_elu<64><<<cdiv(N, 4), 256, 0, stream>>>(ws1, g3, be3, N);

    // Linear 64 -> 32, LN+ELU
    gemm_bias<64, 32><<<cdiv(N, 8), 256, 0, stream>>>(ws1, lw1, lb1, ws0, N);
    ln_elu<32><<<cdiv(N, 4), 256, 0, stream>>>(ws0, g4, be4, N);

    // Linear 32 -> 32 -> out
    gemm_bias<32, 32><<<cdiv(N, 8), 256, 0, stream>>>(ws0, lw2, lb2, out, N);
}

// Round 2
// 1458.853 us; speedup vs baseline: 1.6794x; 1.6794x over previous
//
#include <hip/hip_runtime.h>
#include <math.h>

#define N_NODES 100000
#define LN_EPS 1e-5f

// ---------------- small utility kernels ----------------
__global__ void zero_int(int* __restrict__ p, int n) {
    int i = blockIdx.x * blockDim.x + threadIdx.x;
    if (i < n) p[i] = 0;
}

__global__ void set_int(int* __restrict__ p, int v) {
    if (threadIdx.x == 0 && blockIdx.x == 0) *p = v;
}

__global__ void hist_dst(const int* __restrict__ dst, int* __restrict__ deg, int E) {
    int e = blockIdx.x * blockDim.x + threadIdx.x;
    if (e < E) atomicAdd(&deg[dst[e]], 1);
}

__global__ void deg_to_dinv(const int* __restrict__ deg, float* __restrict__ dinv, int n) {
    int i = blockIdx.x * blockDim.x + threadIdx.x;
    if (i < n) dinv[i] = rsqrtf((float)deg[i] + 1.f);
}

// exclusive scan, 256 elems/block (Hillis-Steele in LDS)
__global__ void scan_block(const int* __restrict__ in, int* __restrict__ out,
                           int* __restrict__ bsums, int n) {
    __shared__ int s[256];
    int i = blockIdx.x * 256 + threadIdx.x;
    int v = (i < n) ? in[i] : 0;
    s[threadIdx.x] = v;
    __syncthreads();
    for (int off = 1; off < 256; off <<= 1) {
        int t = ((int)threadIdx.x >= off) ? s[threadIdx.x - off] : 0;
        __syncthreads();
        s[threadIdx.x] += t;
        __syncthreads();
    }
    if (i < n) out[i] = s[threadIdx.x] - v;  // exclusive
    if (threadIdx.x == 255) bsums[blockIdx.x] = s[255];
}

__global__ void scan_sums(int* __restrict__ bsums, int nb) {
    if (threadIdx.x == 0 && blockIdx.x == 0) {
        int acc = 0;
        for (int i = 0; i < nb; ++i) { int t = bsums[i]; bsums[i] = acc; acc += t; }
    }
}

__global__ void scan_add(int* __restrict__ out, const int* __restrict__ bsums, int n) {
    int i = blockIdx.x * 256 + threadIdx.x;
    if (i < n) out[i] += bsums[blockIdx.x];
}

__global__ void fill_csr(const int* __restrict__ src, const int* __restrict__ dst,
                         const int* __restrict__ offsets, int* __restrict__ cursor,
                         int* __restrict__ csr_src, int E) {
    int e = blockIdx.x * blockDim.x + threadIdx.x;
    if (e < E) {
        int d = dst[e];
        int pos = offsets[d] + atomicAdd(&cursor[d], 1);
        csr_src[pos] = src[e];
    }
}

// ---------------- gemm (X[n,IN_C] @ W[IN_C,OUT_C] (+ bias)) ----------------
template <int IN_C, int OUT_C>
__global__ void gemm_bias(const float* __restrict__ X, const float* __restrict__ W,
                          const float* __restrict__ bias, float* __restrict__ Y, int n) {
    __shared__ float sW[IN_C * OUT_C];
    for (int i = threadIdx.x; i < IN_C * OUT_C; i += blockDim.x) sW[i] = W[i];
    __syncthreads();
    constexpr int NPB = 256 / OUT_C;  // nodes per block
    int node = blockIdx.x * NPB + threadIdx.x / OUT_C;
    int j = threadIdx.x % OUT_C;
    if (node >= n) return;
    const float* xr = X + (size_t)node * IN_C;
    float sum = 0.f;
#pragma unroll
    for (int k = 0; k < IN_C; ++k) sum += xr[k] * sW[k * OUT_C + j];
    if (bias) sum += bias[j];
    Y[(size_t)node * OUT_C + j] = sum;
}

// ---------------- fused gather + self-loop + bias + LN + ELU ----------------
// one wave per node; CSR by dst storing src indices
template <int C>
__global__ void gather_ln_elu(const float* __restrict__ xw, const int* __restrict__ offsets,
                              const int* __restrict__ csr_src, const float* __restrict__ dinv,
                              const float* __restrict__ bias, const float* __restrict__ gamma,
                              const float* __restrict__ beta, float* __restrict__ out, int n) {
    constexpr int PER = C / 64;
    int wave = threadIdx.x >> 6;
    int lane = threadIdx.x & 63;
    int node = blockIdx.x * (blockDim.x >> 6) + wave;
    if (node >= n) return;
    int beg = offsets[node], end = offsets[node + 1];

    float acc[PER];
#pragma unroll
    for (int p = 0; p < PER; ++p) acc[p] = 0.f;

    for (int base = beg; base < end; base += 64) {
        int m = min(64, end - base);
        int myS = (lane < m) ? csr_src[base + lane] : 0;
        float myN = (lane < m) ? dinv[myS] : 0.f;
        for (int j = 0; j < m; ++j) {
            int s = __shfl(myS, j, 64);
            float nm = __shfl(myN, j, 64);
            const float* row = xw + (size_t)s * C;
#pragma unroll
            for (int p = 0; p < PER; ++p) acc[p] += row[lane + p * 64] * nm;
        }
    }

    float dd = dinv[node];
    const float* selfrow = xw + (size_t)node * C;
    float v[PER];
    float sum = 0.f, sq = 0.f;
#pragma unroll
    for (int p = 0; p < PER; ++p) {
        int c = lane + p * 64;
        float y = acc[p] * dd + selfrow[c] * dd * dd + bias[c];
        v[p] = y;
        sum += y;
        sq += y * y;
    }
#pragma unroll
    for (int off = 32; off > 0; off >>= 1) {
        sum += __shfl_xor(sum, off, 64);
        sq += __shfl_xor(sq, off, 64);
    }
    float mu = sum / C;
    float var = sq / C - mu * mu;
    float rs = rsqrtf(var + LN_EPS);
#pragma unroll
    for (int p = 0; p < PER; ++p) {
        int c = lane + p * 64;
        float y = (v[p] - mu) * rs * gamma[c] + beta[c];
        out[(size_t)node * C + c] = y > 0.f ? y : expm1f(y);
    }
}

// ---------------- standalone layernorm + elu (final small layers) ----------------
template <int C>
__global__ void ln_elu(float* __restrict__ h, const float* __restrict__ g,
                       const float* __restrict__ be, int n) {
    int wave = threadIdx.x >> 6;
    int lane = threadIdx.x & 63;
    int node = blockIdx.x * 4 + wave;
    if (node >= n) return;
    float* row = h + (size_t)node * C;
    constexpr int PER = (C + 63) / 64;
    float v[PER];
    float sum = 0.f, sq = 0.f;
#pragma unroll
    for (int idx = 0; idx < PER; ++idx) {
        int c = lane + idx * 64;
        float x = (c < C) ? row[c] : 0.f;
        v[idx] = x;
        sum += x;
        sq += x * x;
    }
#pragma unroll
    for (int off = 32; off > 0; off >>= 1) {
        sum += __shfl_xor(sum, off, 64);
        sq += __shfl_xor(sq, off, 64);
    }
    float mu = sum / C;
    float var = sq / C - mu * mu;
    float rs = rsqrtf(var + LN_EPS);
#pragma unroll
    for (int idx = 0; idx < PER; ++idx) {
        int c = lane + idx * 64;
        if (c < C) {
            float y = (v[idx] - mu) * rs * g[c] + be[c];
            row[c] = y > 0.f ? y : expm1f(y);
        }
    }
}

extern "C" void kernel_launch(void* const* d_in, const int* in_sizes, int n_in,
                              void* d_out, int out_size, void* d_ws, size_t ws_size,
                              hipStream_t stream) {
    const float* x  = (const float*)d_in[0];
    const int* ei   = (const int*)d_in[1];
    const float* W1 = (const float*)d_in[2];
    const float* b1 = (const float*)d_in[3];
    const float* g1 = (const float*)d_in[4];
    const float* be1= (const float*)d_in[5];
    const float* W2 = (const float*)d_in[6];
    const float* b2 = (const float*)d_in[7];
    const float* g2 = (const float*)d_in[8];
    const float* be2= (const float*)d_in[9];
    const float* W3 = (const float*)d_in[10];
    const float* b3 = (const float*)d_in[11];
    const float* g3 = (const float*)d_in[12];
    const float* be3= (const float*)d_in[13];
    const float* lw1= (const float*)d_in[14];
    const float* lb1= (const float*)d_in[15];
    const float* g4 = (const float*)d_in[16];
    const float* be4= (const float*)d_in[17];
    const float* lw2= (const float*)d_in[18];
    const float* lb2= (const float*)d_in[19];
    float* out = (float*)d_out;

    const int E = in_sizes[1] / 2;
    const int* src = ei;
    const int* dst = ei + E;
    const int N = N_NODES;

    // workspace layout
    float* xw      = (float*)d_ws;                    // N*128
    float* h       = xw + (size_t)N * 128;            // N*128
    float* dinv    = h + (size_t)N * 128;             // N
    int*   deg     = (int*)(dinv + N);                // N
    int*   offsets = deg + N;                         // N+1
    int*   cursor  = offsets + N + 1;                 // N
    int*   csr     = cursor + N;                      // E
    int*   bsums   = csr + E;                         // ceil(N/256)

    auto cdiv = [](long long a, long long b) { return (int)((a + b - 1) / b); };
    const int NB = cdiv(N, 256);  // 391

    // ---- build CSR (dst-sorted) + dinv ----
    zero_int<<<NB, 256, 0, stream>>>(deg, N);
    zero_int<<<NB, 256, 0, stream>>>(cursor, N);
    hist_dst<<<cdiv(E, 256), 256, 0, stream>>>(dst, deg, E);
    scan_block<<<NB, 256, 0, stream>>>(deg, offsets, bsums, N);
    scan_sums<<<1, 64, 0, stream>>>(bsums, NB);
    scan_add<<<NB, 256, 0, stream>>>(offsets, bsums, N);
    set_int<<<1, 64, 0, stream>>>(offsets + N, E);
    fill_csr<<<cdiv(E, 256), 256, 0, stream>>>(src, dst, offsets, cursor, csr, E);
    deg_to_dinv<<<NB, 256, 0, stream>>>(deg, dinv, N);

    // ---- Layer 1: 128 -> 64 ----
    gemm_bias<128, 64><<<cdiv(N, 4), 256, 0, stream>>>(x, W1, nullptr, xw, N);
    gather_ln_elu<64><<<cdiv(N, 4), 256, 0, stream>>>(xw, offsets, csr, dinv, b1, g1, be1, h, N);

    // ---- Layer 2: 64 -> 128 ----
    gemm_bias<64, 128><<<cdiv(N, 2), 256, 0, stream>>>(h, W2, nullptr, xw, N);
    gather_ln_elu<128><<<cdiv(N, 4), 256, 0, stream>>>(xw, offsets, csr, dinv, b2, g2, be2, h, N);

    // ---- Layer 3: 128 -> 64 ----
    gemm_bias<128, 64><<<cdiv(N, 4), 256, 0, stream>>>(h, W3, nullptr, xw, N);
    gather_ln_elu<64><<<cdiv(N, 4), 256, 0, stream>>>(xw, offsets, csr, dinv, b3, g3, be3, h, N);

    // ---- Linear 64 -> 32, LN+ELU ----
    gemm_bias<64, 32><<<cdiv(N, 8), 256, 0, stream>>>(h, lw1, lb1, xw, N);
    ln_elu<32><<<cdiv(N, 4), 256, 0, stream>>>(xw, g4, be4, N);

    // ---- Linear 32 -> 32 -> out ----
    gemm_bias<32, 32><<<cdiv(N, 8), 256, 0, stream>>>(xw, lw2, lb2, out, N);
}

// Round 3
// 1000.372 us; speedup vs baseline: 2.4491x; 1.4583x over previous
//
#include <hip/hip_runtime.h>
#include <math.h>

#define N_NODES 100000
#define LN_EPS 1e-5f

// ---------------- small utility kernels ----------------
__global__ void zero_int(int* __restrict__ p, int n) {
    int i = blockIdx.x * blockDim.x + threadIdx.x;
    if (i < n) p[i] = 0;
}

__global__ void set_int(int* __restrict__ p, int v) {
    if (threadIdx.x == 0 && blockIdx.x == 0) *p = v;
}

__global__ void hist_dst(const int* __restrict__ dst, int* __restrict__ deg, int E) {
    int e = blockIdx.x * blockDim.x + threadIdx.x;
    if (e < E) atomicAdd(&deg[dst[e]], 1);
}

__global__ void deg_to_dinv(const int* __restrict__ deg, float* __restrict__ dinv, int n) {
    int i = blockIdx.x * blockDim.x + threadIdx.x;
    if (i < n) dinv[i] = rsqrtf((float)deg[i] + 1.f);
}

// exclusive scan, 256 elems/block
__global__ void scan_block(const int* __restrict__ in, int* __restrict__ out,
                           int* __restrict__ bsums, int n) {
    __shared__ int s[256];
    int i = blockIdx.x * 256 + threadIdx.x;
    int v = (i < n) ? in[i] : 0;
    s[threadIdx.x] = v;
    __syncthreads();
    for (int off = 1; off < 256; off <<= 1) {
        int t = ((int)threadIdx.x >= off) ? s[threadIdx.x - off] : 0;
        __syncthreads();
        s[threadIdx.x] += t;
        __syncthreads();
    }
    if (i < n) out[i] = s[threadIdx.x] - v;  // exclusive
    if (threadIdx.x == 255) bsums[blockIdx.x] = s[255];
}

__global__ void scan_sums(int* __restrict__ bsums, int nb) {
    if (threadIdx.x == 0 && blockIdx.x == 0) {
        int acc = 0;
        for (int i = 0; i < nb; ++i) { int t = bsums[i]; bsums[i] = acc; acc += t; }
    }
}

__global__ void scan_add(int* __restrict__ out, const int* __restrict__ bsums, int n) {
    int i = blockIdx.x * 256 + threadIdx.x;
    if (i < n) out[i] += bsums[blockIdx.x];
}

__global__ void fill_csr(const int* __restrict__ src, const int* __restrict__ dst,
                         const int* __restrict__ offsets, int* __restrict__ cursor,
                         int* __restrict__ csr_src, int E) {
    int e = blockIdx.x * blockDim.x + threadIdx.x;
    if (e < E) {
        int d = dst[e];
        int pos = offsets[d] + atomicAdd(&cursor[d], 1);
        csr_src[pos] = src[e];
    }
}

// ---------------- wave-cooperative gemm, optional fused bias+LN+ELU ----------------
// Each wave handles NPW*G nodes (G = node-groups when OUT_C < 64).
// W staged in LDS; x rows loaded as broadcast float4; NPW*JPL independent accs.
template <int IN_C, int OUT_C, int NPW, bool LN, bool BIAS>
__global__ void gemm_fused(const float* __restrict__ X, const float* __restrict__ W,
                           const float* __restrict__ bias, const float* __restrict__ gamma,
                           const float* __restrict__ beta, float* __restrict__ Y, int n) {
    constexpr int LPN = (OUT_C < 64) ? OUT_C : 64;  // lanes per node
    constexpr int G   = 64 / LPN;                    // node groups per wave
    constexpr int JPL = OUT_C / LPN;                 // cols per lane (1 or 2)
    __shared__ float sW[IN_C * OUT_C];
    for (int i = threadIdx.x; i < IN_C * OUT_C; i += blockDim.x) sW[i] = W[i];
    __syncthreads();

    int wave = threadIdx.x >> 6;
    int lane = threadIdx.x & 63;
    int g  = lane / LPN;
    int jl = lane % LPN;
    long long wid = (long long)blockIdx.x * (blockDim.x >> 6) + wave;
    int nb = (int)(wid * (NPW * G)) + g * NPW;   // first node of my group

    float acc[NPW][JPL];
#pragma unroll
    for (int m = 0; m < NPW; ++m)
#pragma unroll
        for (int jj = 0; jj < JPL; ++jj) acc[m][jj] = 0.f;

    const float4* X4 = (const float4*)X;
#pragma unroll 2
    for (int k4 = 0; k4 < IN_C / 4; ++k4) {
        float4 xv[NPW];
#pragma unroll
        for (int m = 0; m < NPW; ++m) {
            int node = nb + m;
            node = (node < n) ? node : (n - 1);  // clamp (stores guarded later)
            xv[m] = X4[(size_t)node * (IN_C / 4) + k4];
        }
#pragma unroll
        for (int kk = 0; kk < 4; ++kk) {
            int k = k4 * 4 + kk;
            float wj[JPL];
#pragma unroll
            for (int jj = 0; jj < JPL; ++jj) wj[jj] = sW[k * OUT_C + jl * JPL + jj];
#pragma unroll
            for (int m = 0; m < NPW; ++m) {
                float xs = (kk == 0) ? xv[m].x : (kk == 1) ? xv[m].y : (kk == 2) ? xv[m].z : xv[m].w;
#pragma unroll
                for (int jj = 0; jj < JPL; ++jj) acc[m][jj] += xs * wj[jj];
            }
        }
    }

    // epilogue
    float bj[JPL], gj[JPL], btj[JPL];
#pragma unroll
    for (int jj = 0; jj < JPL; ++jj) {
        int col = jl * JPL + jj;
        bj[jj]  = BIAS ? bias[col] : 0.f;
        gj[jj]  = LN ? gamma[col] : 1.f;
        btj[jj] = LN ? beta[col] : 0.f;
    }
#pragma unroll
    for (int m = 0; m < NPW; ++m) {
        int node = nb + m;
        if (LN) {
            float v[JPL];
            float s = 0.f, sq = 0.f;
#pragma unroll
            for (int jj = 0; jj < JPL; ++jj) {
                v[jj] = acc[m][jj] + bj[jj];
                s += v[jj];
                sq += v[jj] * v[jj];
            }
#pragma unroll
            for (int off = LPN / 2; off > 0; off >>= 1) {
                s += __shfl_xor(s, off, 64);
                sq += __shfl_xor(sq, off, 64);
            }
            float mu = s / OUT_C;
            float var = sq / OUT_C - mu * mu;
            float rs = rsqrtf(var + LN_EPS);
            if (node < n) {
#pragma unroll
                for (int jj = 0; jj < JPL; ++jj) {
                    float y = (v[jj] - mu) * rs * gj[jj] + btj[jj];
                    Y[(size_t)node * OUT_C + jl * JPL + jj] = y > 0.f ? y : expm1f(y);
                }
            }
        } else {
            if (node < n) {
#pragma unroll
                for (int jj = 0; jj < JPL; ++jj)
                    Y[(size_t)node * OUT_C + jl * JPL + jj] = acc[m][jj] + bj[jj];
            }
        }
    }
}

// ---------------- fused gather (+ self loop) [+ bias + LN + ELU] ----------------
// one wave per node; CSR by dst storing src indices; C = 64 always.
template <bool LN>
__global__ void gather64(const float* __restrict__ xw, const int* __restrict__ offsets,
                         const int* __restrict__ csr_src, const float* __restrict__ dinv,
                         const float* __restrict__ bias, const float* __restrict__ gamma,
                         const float* __restrict__ beta, float* __restrict__ out, int n) {
    int wave = threadIdx.x >> 6;
    int lane = threadIdx.x & 63;
    int node = blockIdx.x * (blockDim.x >> 6) + wave;
    if (node >= n) return;
    int beg = offsets[node], end = offsets[node + 1];

    float acc = 0.f;
    for (int base = beg; base < end; base += 64) {
        int m = min(64, end - base);
        int myS = (lane < m) ? csr_src[base + lane] : 0;
        float myN = (lane < m) ? dinv[myS] : 0.f;
        int j = 0;
        for (; j + 4 <= m; j += 4) {
            int s0 = __shfl(myS, j, 64), s1 = __shfl(myS, j + 1, 64);
            int s2 = __shfl(myS, j + 2, 64), s3 = __shfl(myS, j + 3, 64);
            float n0 = __shfl(myN, j, 64), n1 = __shfl(myN, j + 1, 64);
            float n2 = __shfl(myN, j + 2, 64), n3 = __shfl(myN, j + 3, 64);
            float r0 = xw[(size_t)s0 * 64 + lane];
            float r1 = xw[(size_t)s1 * 64 + lane];
            float r2 = xw[(size_t)s2 * 64 + lane];
            float r3 = xw[(size_t)s3 * 64 + lane];
            acc += r0 * n0;
            acc += r1 * n1;
            acc += r2 * n2;
            acc += r3 * n3;
        }
        for (; j < m; ++j) {
            int s = __shfl(myS, j, 64);
            float nm = __shfl(myN, j, 64);
            acc += xw[(size_t)s * 64 + lane] * nm;
        }
    }

    float dd = dinv[node];
    float y = acc * dd + xw[(size_t)node * 64 + lane] * dd * dd;
    if (!LN) {
        out[(size_t)node * 64 + lane] = y;
        return;
    }
    y += bias[lane];
    float s = y, sq = y * y;
#pragma unroll
    for (int off = 32; off > 0; off >>= 1) {
        s += __shfl_xor(s, off, 64);
        sq += __shfl_xor(sq, off, 64);
    }
    float mu = s / 64.f;
    float var = sq / 64.f - mu * mu;
    float rs = rsqrtf(var + LN_EPS);
    float z = (y - mu) * rs * gamma[lane] + beta[lane];
    out[(size_t)node * 64 + lane] = z > 0.f ? z : expm1f(z);
}

extern "C" void kernel_launch(void* const* d_in, const int* in_sizes, int n_in,
                              void* d_out, int out_size, void* d_ws, size_t ws_size,
                              hipStream_t stream) {
    const float* x  = (const float*)d_in[0];
    const int* ei   = (const int*)d_in[1];
    const float* W1 = (const float*)d_in[2];
    const float* b1 = (const float*)d_in[3];
    const float* g1 = (const float*)d_in[4];
    const float* be1= (const float*)d_in[5];
    const float* W2 = (const float*)d_in[6];
    const float* b2 = (const float*)d_in[7];
    const float* g2 = (const float*)d_in[8];
    const float* be2= (const float*)d_in[9];
    const float* W3 = (const float*)d_in[10];
    const float* b3 = (const float*)d_in[11];
    const float* g3 = (const float*)d_in[12];
    const float* be3= (const float*)d_in[13];
    const float* lw1= (const float*)d_in[14];
    const float* lb1= (const float*)d_in[15];
    const float* g4 = (const float*)d_in[16];
    const float* be4= (const float*)d_in[17];
    const float* lw2= (const float*)d_in[18];
    const float* lb2= (const float*)d_in[19];
    float* out = (float*)d_out;

    const int E = in_sizes[1] / 2;
    const int* src = ei;
    const int* dst = ei + E;
    const int N = N_NODES;

    // workspace layout
    float* bufA    = (float*)d_ws;                    // N*128
    float* bufB    = bufA + (size_t)N * 128;          // N*128
    float* dinv    = bufB + (size_t)N * 128;          // N
    int*   deg     = (int*)(dinv + N);                // N
    int*   offsets = deg + N;                         // N+1
    int*   cursor  = offsets + N + 1;                 // N
    int*   csr     = cursor + N;                      // E
    int*   bsums   = csr + E;                         // ceil(N/256)

    auto cdiv = [](long long a, long long b) { return (int)((a + b - 1) / b); };
    const int NB = cdiv(N, 256);

    // ---- build CSR (dst-sorted) + dinv ----
    zero_int<<<NB, 256, 0, stream>>>(deg, N);
    zero_int<<<NB, 256, 0, stream>>>(cursor, N);
    hist_dst<<<cdiv(E, 256), 256, 0, stream>>>(dst, deg, E);
    scan_block<<<NB, 256, 0, stream>>>(deg, offsets, bsums, N);
    scan_sums<<<1, 64, 0, stream>>>(bsums, NB);
    scan_add<<<NB, 256, 0, stream>>>(offsets, bsums, N);
    set_int<<<1, 64, 0, stream>>>(offsets + N, E);
    fill_csr<<<cdiv(E, 256), 256, 0, stream>>>(src, dst, offsets, cursor, csr, E);
    deg_to_dinv<<<NB, 256, 0, stream>>>(deg, dinv, N);

    // ---- Layer 1: xw1 = x @ W1 (128->64); h1 = LN_ELU(gather + b1) ----
    gemm_fused<128, 64, 16, false, false><<<cdiv(N, 64), 256, 0, stream>>>(
        x, W1, nullptr, nullptr, nullptr, bufA, N);
    gather64<true><<<cdiv(N, 4), 256, 0, stream>>>(bufA, offsets, csr, dinv, b1, g1, be1, bufB, N);

    // ---- Layer 2 (aggregate-first): a2 = gather(h1); h2 = LN_ELU(a2 @ W2 + b2) ----
    gather64<false><<<cdiv(N, 4), 256, 0, stream>>>(bufB, offsets, csr, dinv, nullptr, nullptr, nullptr, bufA, N);
    gemm_fused<64, 128, 8, true, true><<<cdiv(N, 32), 256, 0, stream>>>(
        bufA, W2, b2, g2, be2, bufB, N);

    // ---- Layer 3: xw3 = h2 @ W3 (128->64); h3 = LN_ELU(gather + b3) ----
    gemm_fused<128, 64, 16, false, false><<<cdiv(N, 64), 256, 0, stream>>>(
        bufB, W3, nullptr, nullptr, nullptr, bufA, N);
    gather64<true><<<cdiv(N, 4), 256, 0, stream>>>(bufA, offsets, csr, dinv, b3, g3, be3, bufB, N);

    // ---- lin1: t = LN_ELU(h3 @ lw1 + lb1) (64->32) ----
    gemm_fused<64, 32, 8, true, true><<<cdiv(N, 64), 256, 0, stream>>>(
        bufB, lw1, lb1, g4, be4, bufA, N);

    // ---- lin2: out = t @ lw2 + lb2 (32->32) ----
    gemm_fused<32, 32, 8, false, true><<<cdiv(N, 64), 256, 0, stream>>>(
        bufA, lw2, lb2, nullptr, nullptr, out, N);
}

// Round 4
// 951.954 us; speedup vs baseline: 2.5736x; 1.0509x over previous
//
#include <hip/hip_runtime.h>
#include <math.h>

#define N_NODES 100000
#define LN_EPS 1e-5f

// ---------------- small utility kernels ----------------
__global__ void zero_int(int* __restrict__ p, int n) {
    int i = blockIdx.x * blockDim.x + threadIdx.x;
    if (i < n) p[i] = 0;
}

__global__ void set_int(int* __restrict__ p, int v) {
    if (threadIdx.x == 0 && blockIdx.x == 0) *p = v;
}

__global__ void hist_dst(const int* __restrict__ dst, int* __restrict__ deg, int E) {
    int e = blockIdx.x * blockDim.x + threadIdx.x;
    if (e < E) atomicAdd(&deg[dst[e]], 1);
}

__global__ void deg_to_dinv(const int* __restrict__ deg, float* __restrict__ dinv, int n) {
    int i = blockIdx.x * blockDim.x + threadIdx.x;
    if (i < n) dinv[i] = rsqrtf((float)deg[i] + 1.f);
}

// exclusive scan, 256 elems/block
__global__ void scan_block(const int* __restrict__ in, int* __restrict__ out,
                           int* __restrict__ bsums, int n) {
    __shared__ int s[256];
    int i = blockIdx.x * 256 + threadIdx.x;
    int v = (i < n) ? in[i] : 0;
    s[threadIdx.x] = v;
    __syncthreads();
    for (int off = 1; off < 256; off <<= 1) {
        int t = ((int)threadIdx.x >= off) ? s[threadIdx.x - off] : 0;
        __syncthreads();
        s[threadIdx.x] += t;
        __syncthreads();
    }
    if (i < n) out[i] = s[threadIdx.x] - v;  // exclusive
    if (threadIdx.x == 255) bsums[blockIdx.x] = s[255];
}

__global__ void scan_sums(int* __restrict__ bsums, int nb) {
    if (threadIdx.x == 0 && blockIdx.x == 0) {
        int acc = 0;
        for (int i = 0; i < nb; ++i) { int t = bsums[i]; bsums[i] = acc; acc += t; }
    }
}

__global__ void scan_add(int* __restrict__ out, const int* __restrict__ bsums, int n) {
    int i = blockIdx.x * 256 + threadIdx.x;
    if (i < n) out[i] += bsums[blockIdx.x];
}

__global__ void fill_csr(const int* __restrict__ src, const int* __restrict__ dst,
                         const int* __restrict__ offsets, int* __restrict__ cursor,
                         int* __restrict__ csr_src, int E) {
    int e = blockIdx.x * blockDim.x + threadIdx.x;
    if (e < E) {
        int d = dst[e];
        int pos = offsets[d] + atomicAdd(&cursor[d], 1);
        csr_src[pos] = src[e];
    }
}

// ---------------- LDS-staged wave-cooperative gemm (+bias+LN+ELU) ----------------
// Each wave owns NPW*G nodes. x tile staged per-wave in LDS (coalesced float4),
// re-read as uniform ds_read_b128 broadcasts (free). W in LDS, b32 stride-OUT_C
// reads (2-way = free). NPW*JPL accumulators per lane -> VALU-bound.
template <int IN_C, int OUT_C, int NPW, bool LN, bool BIAS>
__launch_bounds__(256)
__global__ void gemm_tile(const float* __restrict__ X, const float* __restrict__ W,
                          const float* __restrict__ bias, const float* __restrict__ gamma,
                          const float* __restrict__ beta, float* __restrict__ Y, int n) {
    constexpr int LPN = (OUT_C < 64) ? OUT_C : 64;  // lanes per node-group
    constexpr int G   = 64 / LPN;                   // node groups per wave
    constexpr int JPL = (OUT_C + 63) / 64;          // cols per lane
    constexpr int NW  = 4;                          // waves per block
    constexpr int NPWG = NPW * G;                   // nodes per wave
    constexpr int C4  = IN_C / 4;

    __shared__ float sW[IN_C * OUT_C];
    __shared__ float4 sX[NW][NPWG * C4];

    for (int i = threadIdx.x; i < IN_C * OUT_C; i += 256) sW[i] = W[i];

    int wv = threadIdx.x >> 6, lane = threadIdx.x & 63;
    int g = lane / LPN;
    int col = lane % LPN;
    int nb = (blockIdx.x * NW + wv) * NPWG;  // wave's first node

    // stage x rows [nb, nb+NPWG) -- coalesced float4
    const float4* X4 = (const float4*)X;
#pragma unroll
    for (int i = 0; i < NPWG * C4 / 64; ++i) {
        int idx = i * 64 + lane;
        int row = idx / C4, c4 = idx % C4;
        int node = nb + row;
        node = (node < n) ? node : (n - 1);
        sX[wv][idx] = X4[(size_t)node * C4 + c4];
    }
    __syncthreads();  // sW ready (sX is wave-private)

    float acc[NPW][JPL];
#pragma unroll
    for (int m = 0; m < NPW; ++m)
#pragma unroll
        for (int jj = 0; jj < JPL; ++jj) acc[m][jj] = 0.f;

    for (int k4 = 0; k4 < C4; ++k4) {
        float wf[4][JPL];
#pragma unroll
        for (int kk = 0; kk < 4; ++kk)
#pragma unroll
            for (int jj = 0; jj < JPL; ++jj)
                wf[kk][jj] = sW[(k4 * 4 + kk) * OUT_C + col + jj * 64];
#pragma unroll
        for (int m = 0; m < NPW; ++m) {
            float4 xv = sX[wv][(g * NPW + m) * C4 + k4];  // uniform per group: broadcast
#pragma unroll
            for (int kk = 0; kk < 4; ++kk) {
                float xs = (kk == 0) ? xv.x : (kk == 1) ? xv.y : (kk == 2) ? xv.z : xv.w;
#pragma unroll
                for (int jj = 0; jj < JPL; ++jj) acc[m][jj] += xs * wf[kk][jj];
            }
        }
    }

    // epilogue
    float bj[JPL], gj[JPL], btj[JPL];
#pragma unroll
    for (int jj = 0; jj < JPL; ++jj) {
        int c = col + jj * 64;
        bj[jj]  = BIAS ? bias[c] : 0.f;
        gj[jj]  = LN ? gamma[c] : 1.f;
        btj[jj] = LN ? beta[c] : 0.f;
    }
#pragma unroll
    for (int m = 0; m < NPW; ++m) {
        int node = nb + g * NPW + m;
        if (LN) {
            float v[JPL];
            float s = 0.f, sq = 0.f;
#pragma unroll
            for (int jj = 0; jj < JPL; ++jj) {
                v[jj] = acc[m][jj] + bj[jj];
                s += v[jj];
                sq += v[jj] * v[jj];
            }
#pragma unroll
            for (int off = LPN / 2; off > 0; off >>= 1) {
                s += __shfl_xor(s, off, 64);
                sq += __shfl_xor(sq, off, 64);
            }
            float mu = s / OUT_C;
            float var = sq / OUT_C - mu * mu;
            float rs = rsqrtf(var + LN_EPS);
            if (node < n) {
#pragma unroll
                for (int jj = 0; jj < JPL; ++jj) {
                    float y = (v[jj] - mu) * rs * gj[jj] + btj[jj];
                    Y[(size_t)node * OUT_C + col + jj * 64] = y > 0.f ? y : expm1f(y);
                }
            }
        } else if (node < n) {
#pragma unroll
            for (int jj = 0; jj < JPL; ++jj)
                Y[(size_t)node * OUT_C + col + jj * 64] = acc[m][jj] + bj[jj];
        }
    }
}

// ---------------- fused gather (+ self loop) [+ bias + LN + ELU] ----------------
template <bool LN>
__global__ void gather64(const float* __restrict__ xw, const int* __restrict__ offsets,
                         const int* __restrict__ csr_src, const float* __restrict__ dinv,
                         const float* __restrict__ bias, const float* __restrict__ gamma,
                         const float* __restrict__ beta, float* __restrict__ out, int n) {
    int wave = threadIdx.x >> 6;
    int lane = threadIdx.x & 63;
    int node = blockIdx.x * (blockDim.x >> 6) + wave;
    if (node >= n) return;
    int beg = offsets[node], end = offsets[node + 1];

    float acc = 0.f;
    for (int base = beg; base < end; base += 64) {
        int m = min(64, end - base);
        int myS = (lane < m) ? csr_src[base + lane] : 0;
        float myN = (lane < m) ? dinv[myS] : 0.f;
        int j = 0;
        for (; j + 4 <= m; j += 4) {
            int s0 = __shfl(myS, j, 64), s1 = __shfl(myS, j + 1, 64);
            int s2 = __shfl(myS, j + 2, 64), s3 = __shfl(myS, j + 3, 64);
            float n0 = __shfl(myN, j, 64), n1 = __shfl(myN, j + 1, 64);
            float n2 = __shfl(myN, j + 2, 64), n3 = __shfl(myN, j + 3, 64);
            float r0 = xw[(size_t)s0 * 64 + lane];
            float r1 = xw[(size_t)s1 * 64 + lane];
            float r2 = xw[(size_t)s2 * 64 + lane];
            float r3 = xw[(size_t)s3 * 64 + lane];
            acc += r0 * n0;
            acc += r1 * n1;
            acc += r2 * n2;
            acc += r3 * n3;
        }
        for (; j < m; ++j) {
            int s = __shfl(myS, j, 64);
            float nm = __shfl(myN, j, 64);
            acc += xw[(size_t)s * 64 + lane] * nm;
        }
    }

    float dd = dinv[node];
    float y = acc * dd + xw[(size_t)node * 64 + lane] * dd * dd;
    if (!LN) {
        out[(size_t)node * 64 + lane] = y;
        return;
    }
    y += bias[lane];
    float s = y, sq = y * y;
#pragma unroll
    for (int off = 32; off > 0; off >>= 1) {
        s += __shfl_xor(s, off, 64);
        sq += __shfl_xor(sq, off, 64);
    }
    float mu = s / 64.f;
    float var = sq / 64.f - mu * mu;
    float rs = rsqrtf(var + LN_EPS);
    float z = (y - mu) * rs * gamma[lane] + beta[lane];
    out[(size_t)node * 64 + lane] = z > 0.f ? z : expm1f(z);
}

extern "C" void kernel_launch(void* const* d_in, const int* in_sizes, int n_in,
                              void* d_out, int out_size, void* d_ws, size_t ws_size,
                              hipStream_t stream) {
    const float* x  = (const float*)d_in[0];
    const int* ei   = (const int*)d_in[1];
    const float* W1 = (const float*)d_in[2];
    const float* b1 = (const float*)d_in[3];
    const float* g1 = (const float*)d_in[4];
    const float* be1= (const float*)d_in[5];
    const float* W2 = (const float*)d_in[6];
    const float* b2 = (const float*)d_in[7];
    const float* g2 = (const float*)d_in[8];
    const float* be2= (const float*)d_in[9];
    const float* W3 = (const float*)d_in[10];
    const float* b3 = (const float*)d_in[11];
    const float* g3 = (const float*)d_in[12];
    const float* be3= (const float*)d_in[13];
    const float* lw1= (const float*)d_in[14];
    const float* lb1= (const float*)d_in[15];
    const float* g4 = (const float*)d_in[16];
    const float* be4= (const float*)d_in[17];
    const float* lw2= (const float*)d_in[18];
    const float* lb2= (const float*)d_in[19];
    float* out = (float*)d_out;

    const int E = in_sizes[1] / 2;
    const int* src = ei;
    const int* dst = ei + E;
    const int N = N_NODES;

    // workspace layout
    float* bufA    = (float*)d_ws;                    // N*128
    float* bufB    = bufA + (size_t)N * 128;          // N*128
    float* dinv    = bufB + (size_t)N * 128;          // N
    int*   deg     = (int*)(dinv + N);                // N
    int*   offsets = deg + N;                         // N+1
    int*   cursor  = offsets + N + 1;                 // N
    int*   csr     = cursor + N;                      // E
    int*   bsums   = csr + E;                         // ceil(N/256)

    auto cdiv = [](long long a, long long b) { return (int)((a + b - 1) / b); };
    const int NB = cdiv(N, 256);

    // ---- build CSR (dst-sorted) + dinv ----
    zero_int<<<NB, 256, 0, stream>>>(deg, N);
    zero_int<<<NB, 256, 0, stream>>>(cursor, N);
    hist_dst<<<cdiv(E, 256), 256, 0, stream>>>(dst, deg, E);
    scan_block<<<NB, 256, 0, stream>>>(deg, offsets, bsums, N);
    scan_sums<<<1, 64, 0, stream>>>(bsums, NB);
    scan_add<<<NB, 256, 0, stream>>>(offsets, bsums, N);
    set_int<<<1, 64, 0, stream>>>(offsets + N, E);
    fill_csr<<<cdiv(E, 256), 256, 0, stream>>>(src, dst, offsets, cursor, csr, E);
    deg_to_dinv<<<NB, 256, 0, stream>>>(deg, dinv, N);

    // ---- Layer 1: xw1 = x @ W1 (128->64); h1 = LN_ELU(gather + b1) ----
    gemm_tile<128, 64, 16, false, false><<<cdiv(N, 64), 256, 0, stream>>>(
        x, W1, nullptr, nullptr, nullptr, bufA, N);
    gather64<true><<<cdiv(N, 4), 256, 0, stream>>>(bufA, offsets, csr, dinv, b1, g1, be1, bufB, N);

    // ---- Layer 2 (aggregate-first): a2 = gather(h1); h2 = LN_ELU(a2 @ W2 + b2) ----
    gather64<false><<<cdiv(N, 4), 256, 0, stream>>>(bufB, offsets, csr, dinv, nullptr, nullptr, nullptr, bufA, N);
    gemm_tile<64, 128, 16, true, true><<<cdiv(N, 64), 256, 0, stream>>>(
        bufA, W2, b2, g2, be2, bufB, N);

    // ---- Layer 3: xw3 = h2 @ W3 (128->64); h3 = LN_ELU(gather + b3) ----
    gemm_tile<128, 64, 16, false, false><<<cdiv(N, 64), 256, 0, stream>>>(
        bufB, W3, nullptr, nullptr, nullptr, bufA, N);
    gather64<true><<<cdiv(N, 4), 256, 0, stream>>>(bufA, offsets, csr, dinv, b3, g3, be3, bufB, N);

    // ---- lin1: t = LN_ELU(h3 @ lw1 + lb1) (64->32) ----
    gemm_tile<64, 32, 16, true, true><<<cdiv(N, 128), 256, 0, stream>>>(
        bufB, lw1, lb1, g4, be4, bufA, N);

    // ---- lin2: out = t @ lw2 + lb2 (32->32) ----
    gemm_tile<32, 32, 16, false, true><<<cdiv(N, 128), 256, 0, stream>>>(
        bufA, lw2, lb2, nullptr, nullptr, out, N);
}